// Round 1
// baseline (2141.132 us; speedup 1.0000x reference)
//
#include <hip/hip_runtime.h>

#define D 256

typedef __attribute__((ext_vector_type(8))) short short8;
typedef __attribute__((ext_vector_type(4))) float f32x4;

__device__ __forceinline__ ushort f2b(float f) {
    unsigned u = __float_as_uint(f);
    u += 0x7fffu + ((u >> 16) & 1u);   // round-to-nearest-even
    return (ushort)(u >> 16);
}
__device__ __forceinline__ float b2f(ushort h) {
    return __uint_as_float(((unsigned)h) << 16);
}

// ---------------- CSR build ----------------

__global__ void zero_int_kernel(int* __restrict__ p, int n) {
    int i = blockIdx.x * blockDim.x + threadIdx.x;
    if (i < n) p[i] = 0;
}

__global__ void hist_kernel(const int* __restrict__ rows, int* __restrict__ cnt, int e) {
    int stride = gridDim.x * blockDim.x;
    for (int i = blockIdx.x * blockDim.x + threadIdx.x; i < e; i += stride)
        atomicAdd(&cnt[rows[i]], 1);
}

__global__ void scan_a_kernel(const int* __restrict__ cnt, int* __restrict__ bsums, int n) {
    __shared__ int s[256];
    int t = threadIdx.x;
    int i = blockIdx.x * 256 + t;
    s[t] = (i < n) ? cnt[i] : 0;
    __syncthreads();
    for (int off = 128; off > 0; off >>= 1) {
        if (t < off) s[t] += s[t + off];
        __syncthreads();
    }
    if (t == 0) bsums[blockIdx.x] = s[0];
}

__global__ void scan_b_kernel(const int* __restrict__ bsums, int* __restrict__ bbase, int nb) {
    __shared__ int s[512];
    int t = threadIdx.x;
    int v = (t < nb) ? bsums[t] : 0;
    s[t] = v;
    __syncthreads();
    for (int off = 1; off < 512; off <<= 1) {
        int x = (t >= off) ? s[t - off] : 0;
        __syncthreads();
        s[t] += x;
        __syncthreads();
    }
    bbase[t] = s[t] - v;   // exclusive base per block
}

__global__ void scan_c_kernel(const int* __restrict__ cnt, const int* __restrict__ bbase,
                              int* __restrict__ row_ptr, int n, int e) {
    __shared__ int s[256];
    int t = threadIdx.x;
    int i = blockIdx.x * 256 + t;
    int v = (i < n) ? cnt[i] : 0;
    s[t] = v;
    __syncthreads();
    for (int off = 1; off < 256; off <<= 1) {
        int x = (t >= off) ? s[t - off] : 0;
        __syncthreads();
        s[t] += x;
        __syncthreads();
    }
    if (i < n) row_ptr[i] = bbase[blockIdx.x] + s[t] - v;
    if (i == 0) row_ptr[n] = e;
}

__global__ void scatter_kernel(const int* __restrict__ rows, const int* __restrict__ cols,
                               const float* __restrict__ vals, const int* __restrict__ row_ptr,
                               int* __restrict__ cur, int2* __restrict__ edges, int e) {
    int stride = gridDim.x * blockDim.x;
    for (int i = blockIdx.x * blockDim.x + threadIdx.x; i < e; i += stride) {
        int r = rows[i];
        int p = row_ptr[r] + atomicAdd(&cur[r], 1);
        edges[p] = make_int2(cols[i], __float_as_int(vals[i]));
    }
}

// ---------------- W transpose + bf16 convert ----------------
// WT[c][k] = bf16(W[k][c])
__global__ void wconv_kernel(const float* __restrict__ W, ushort* __restrict__ WT) {
    int idx = blockIdx.x * 256 + threadIdx.x;   // 65536 total
    int c = idx >> 8, k = idx & 255;
    WT[c * 256 + k] = f2b(W[k * 256 + c]);
}

// ---------------- GEMM: F(bf16)[M][256] = X(f32)[M][256] @ W ----------------
#define APAD 40   // padded LDS row (bf16 elems): 80B rows keep 16B alignment, ~2-way banks

__global__ __launch_bounds__(256) void gemm_kernel(const float* __restrict__ X,
                                                   const ushort* __restrict__ WT,
                                                   ushort* __restrict__ F, int M) {
    __shared__ ushort As[64 * APAD];
    __shared__ ushort Bs[64 * APAD];
    int tid = threadIdx.x;
    int r0 = blockIdx.x * 64, c0 = blockIdx.y * 64;
    int w = tid >> 6, lane = tid & 63;
    int wr = w >> 1, wc = w & 1;
    int lo = lane & 15, hi = lane >> 4;
    f32x4 acc[2][2] = {};

    int srow = tid >> 2;           // 0..63
    int skoff = (tid & 3) * 8;     // 0,8,16,24
    int arow = r0 + srow; if (arow > M - 1) arow = M - 1;
    const float*  ap = X  + (size_t)arow * 256 + skoff;
    const ushort* bp = WT + (size_t)(c0 + srow) * 256 + skoff;

    for (int kk = 0; kk < 256; kk += 32) {
        float4 x0 = *(const float4*)(ap + kk);
        float4 x1 = *(const float4*)(ap + kk + 4);
        short8 bv = *(const short8*)(bp + kk);
        __syncthreads();
        ushort a8[8] = {f2b(x0.x), f2b(x0.y), f2b(x0.z), f2b(x0.w),
                        f2b(x1.x), f2b(x1.y), f2b(x1.z), f2b(x1.w)};
        *(short8*)&As[srow * APAD + skoff] = *(const short8*)a8;
        *(short8*)&Bs[srow * APAD + skoff] = bv;
        __syncthreads();
        // same (hi,j)->k mapping for A and B: correctness invariant to HW k-permutation
        short8 a0 = *(const short8*)&As[(wr * 32 +      lo) * APAD + hi * 8];
        short8 a1 = *(const short8*)&As[(wr * 32 + 16 + lo) * APAD + hi * 8];
        short8 b0 = *(const short8*)&Bs[(wc * 32 +      lo) * APAD + hi * 8];
        short8 b1 = *(const short8*)&Bs[(wc * 32 + 16 + lo) * APAD + hi * 8];
        acc[0][0] = __builtin_amdgcn_mfma_f32_16x16x32_bf16(a0, b0, acc[0][0], 0, 0, 0);
        acc[0][1] = __builtin_amdgcn_mfma_f32_16x16x32_bf16(a0, b1, acc[0][1], 0, 0, 0);
        acc[1][0] = __builtin_amdgcn_mfma_f32_16x16x32_bf16(a1, b0, acc[1][0], 0, 0, 0);
        acc[1][1] = __builtin_amdgcn_mfma_f32_16x16x32_bf16(a1, b1, acc[1][1], 0, 0, 0);
    }
    // C/D layout (HW-verified): col = lane&15, row = (lane>>4)*4 + reg
    for (int mi = 0; mi < 2; ++mi)
        for (int ni = 0; ni < 2; ++ni)
            for (int i = 0; i < 4; ++i) {
                int row = r0 + wr * 32 + mi * 16 + hi * 4 + i;
                int col = c0 + wc * 32 + ni * 16 + lo;
                if (row < M) F[(size_t)row * 256 + col] = f2b(acc[mi][ni][i]);
            }
}

// ---------------- SpMM: one wave per output row, atomic-free ----------------
// mode bit0: add previous out; bit1: apply relu
__global__ __launch_bounds__(256) void spmm_kernel(const int* __restrict__ row_ptr,
                                                   const int2* __restrict__ edges,
                                                   const ushort* __restrict__ F,
                                                   float* __restrict__ out, int n, int mode) {
    int w = threadIdx.x >> 6, lane = threadIdx.x & 63;
    int r = blockIdx.x * 4 + w;
    if (r >= n) return;
    int e0 = row_ptr[r], e1 = row_ptr[r + 1];
    int doff = lane * 4;   // each lane owns 4 of 256 cols -> wave load = 512B contiguous
    float ax = 0.f, ay = 0.f, az = 0.f, aw = 0.f;
    for (int e = e0; e < e1; ++e) {
        int2 ev = edges[e];
        const ushort4 v = *(const ushort4*)(F + (size_t)ev.x * 256 + doff);
        float val = __int_as_float(ev.y);
        ax += val * b2f(v.x);
        ay += val * b2f(v.y);
        az += val * b2f(v.z);
        aw += val * b2f(v.w);
    }
    float* op = out + (size_t)r * 256 + doff;
    if (mode & 1) {
        float4 prev = *(const float4*)op;
        ax += prev.x; ay += prev.y; az += prev.z; aw += prev.w;
    }
    if (mode & 2) {
        ax = fmaxf(ax, 0.f); ay = fmaxf(ay, 0.f);
        az = fmaxf(az, 0.f); aw = fmaxf(aw, 0.f);
    }
    *(float4*)op = make_float4(ax, ay, az, aw);
}

extern "C" void kernel_launch(void* const* d_in, const int* in_sizes, int n_in,
                              void* d_out, int out_size, void* d_ws, size_t ws_size,
                              hipStream_t stream) {
    const float* X    = (const float*)d_in[0];
    const float* W    = (const float*)d_in[1];
    const float* vals = (const float*)d_in[2];
    const int*   rows = (const int*)d_in[3];
    const int*   cols = (const int*)d_in[4];
    int n    = in_sizes[0] / D;         // 100000
    int hops = in_sizes[1] / (D * D);   // 3
    int e    = in_sizes[2] / hops;      // 3200000
    int nblk = (n + 255) / 256;         // 391 (must be <= 512 for scan_b)

    char* wsb = (char*)d_ws;
    size_t off = 0;
    auto alloc = [&](size_t bytes) -> void* {
        void* p = wsb + off;
        off += (bytes + 255) & ~(size_t)255;
        return p;
    };
    ushort* WT      = (ushort*)alloc((size_t)D * D * sizeof(ushort));
    ushort* F       = (ushort*)alloc((size_t)n * D * sizeof(ushort));
    int*    cnt     = (int*)   alloc((size_t)nblk * 256 * sizeof(int));
    int*    bsums   = (int*)   alloc(512 * sizeof(int));
    int*    bbase   = (int*)   alloc(512 * sizeof(int));
    int*    row_ptr = (int*)   alloc((size_t)(n + 1) * sizeof(int));
    int2*   edges   = (int2*)  alloc((size_t)e * sizeof(int2));

    float* out = (float*)d_out;

    for (int h = 0; h < hops; ++h) {
        const int*   rh = rows + (size_t)h * e;
        const int*   ch = cols + (size_t)h * e;
        const float* vh = vals + (size_t)h * e;

        zero_int_kernel<<<nblk, 256, 0, stream>>>(cnt, nblk * 256);
        hist_kernel<<<2048, 256, 0, stream>>>(rh, cnt, e);
        scan_a_kernel<<<nblk, 256, 0, stream>>>(cnt, bsums, n);
        scan_b_kernel<<<1, 512, 0, stream>>>(bsums, bbase, nblk);
        scan_c_kernel<<<nblk, 256, 0, stream>>>(cnt, bbase, row_ptr, n, e);
        zero_int_kernel<<<nblk, 256, 0, stream>>>(cnt, nblk * 256);
        scatter_kernel<<<2048, 256, 0, stream>>>(rh, ch, vh, row_ptr, cnt, edges, e);

        wconv_kernel<<<(D * D) / 256, 256, 0, stream>>>(W + (size_t)h * D * D, WT);
        gemm_kernel<<<dim3((n + 63) / 64, D / 64), 256, 0, stream>>>(X, WT, F, n);

        int mode = (h > 0 ? 1 : 0) | (h == hops - 1 ? 2 : 0);
        spmm_kernel<<<(n + 3) / 4, 256, 0, stream>>>(row_ptr, edges, F, out, n, mode);
    }
}

// Round 2
// 1647.921 us; speedup vs baseline: 1.2993x; 1.2993x over previous
//
#include <hip/hip_runtime.h>

#define D 256

typedef __attribute__((ext_vector_type(8))) short short8;
typedef __attribute__((ext_vector_type(4))) float f32x4;

__device__ __forceinline__ ushort f2b(float f) {
    unsigned u = __float_as_uint(f);
    u += 0x7fffu + ((u >> 16) & 1u);   // round-to-nearest-even
    return (ushort)(u >> 16);
}
__device__ __forceinline__ float b2f(ushort h) {
    return __uint_as_float(((unsigned)h) << 16);
}

// ---------------- CSR build ----------------

__global__ void zero_int_kernel(int* __restrict__ p, int n) {
    int i = blockIdx.x * blockDim.x + threadIdx.x;
    if (i < n) p[i] = 0;
}

__global__ void hist_kernel(const int* __restrict__ rows, int* __restrict__ cnt, int e) {
    int stride = gridDim.x * blockDim.x;
    for (int i = blockIdx.x * blockDim.x + threadIdx.x; i < e; i += stride)
        atomicAdd(&cnt[rows[i]], 1);
}

__global__ void scan_a_kernel(const int* __restrict__ cnt, int* __restrict__ bsums, int n) {
    __shared__ int s[256];
    int t = threadIdx.x;
    int i = blockIdx.x * 256 + t;
    s[t] = (i < n) ? cnt[i] : 0;
    __syncthreads();
    for (int off = 128; off > 0; off >>= 1) {
        if (t < off) s[t] += s[t + off];
        __syncthreads();
    }
    if (t == 0) bsums[blockIdx.x] = s[0];
}

__global__ void scan_b_kernel(const int* __restrict__ bsums, int* __restrict__ bbase, int nb) {
    __shared__ int s[512];
    int t = threadIdx.x;
    int v = (t < nb) ? bsums[t] : 0;
    s[t] = v;
    __syncthreads();
    for (int off = 1; off < 512; off <<= 1) {
        int x = (t >= off) ? s[t - off] : 0;
        __syncthreads();
        s[t] += x;
        __syncthreads();
    }
    bbase[t] = s[t] - v;   // exclusive base per block
}

__global__ void scan_c_kernel(const int* __restrict__ cnt, const int* __restrict__ bbase,
                              int* __restrict__ row_ptr, int n, int e) {
    __shared__ int s[256];
    int t = threadIdx.x;
    int i = blockIdx.x * 256 + t;
    int v = (i < n) ? cnt[i] : 0;
    s[t] = v;
    __syncthreads();
    for (int off = 1; off < 256; off <<= 1) {
        int x = (t >= off) ? s[t - off] : 0;
        __syncthreads();
        s[t] += x;
        __syncthreads();
    }
    if (i < n) row_ptr[i] = bbase[blockIdx.x] + s[t] - v;
    if (i == 0) row_ptr[n] = e;
}

// idxoff = hop * N for the fused-F layout (0 for per-hop fallback)
__global__ void scatter_kernel(const int* __restrict__ rows, const int* __restrict__ cols,
                               const float* __restrict__ vals, const int* __restrict__ row_ptr,
                               int* __restrict__ cur, int2* __restrict__ edges, int e, int idxoff) {
    int stride = gridDim.x * blockDim.x;
    for (int i = blockIdx.x * blockDim.x + threadIdx.x; i < e; i += stride) {
        int r = rows[i];
        int p = row_ptr[r] + atomicAdd(&cur[r], 1);
        edges[p] = make_int2(idxoff + cols[i], __float_as_int(vals[i]));
    }
}

// ---------------- W transpose + bf16 convert (all hops) ----------------
// WT[h][c][k] = bf16(W[h][k][c])
__global__ void wconv_kernel(const float* __restrict__ W, ushort* __restrict__ WT, int total) {
    int idx = blockIdx.x * 256 + threadIdx.x;
    if (idx >= total) return;
    int h = idx >> 16;
    int c = (idx >> 8) & 255, k = idx & 255;
    WT[(h << 16) + c * 256 + k] = f2b(W[(h << 16) + k * 256 + c]);
}

#define APAD 40   // padded LDS row (bf16 elems): 80B rows keep 16B alignment

// ---------------- fused GEMM: F[h][M][256] = bf16(X @ W_h), h = 0..2 ----------------
__global__ __launch_bounds__(256) void gemm3_kernel(const float* __restrict__ X,
                                                    const ushort* __restrict__ WT,
                                                    ushort* __restrict__ F, int M) {
    __shared__ ushort As[64 * APAD];
    __shared__ ushort Bs[3][64 * APAD];
    int tid = threadIdx.x;
    int r0 = blockIdx.x * 64, c0 = blockIdx.y * 64;
    int w = tid >> 6, lane = tid & 63;
    int wr = w >> 1, wc = w & 1;
    int lo = lane & 15, hi = lane >> 4;
    f32x4 acc[3][2][2] = {};

    int srow = tid >> 2;           // 0..63
    int skoff = (tid & 3) * 8;     // 0,8,16,24
    int arow = r0 + srow; if (arow > M - 1) arow = M - 1;
    const float*  ap = X + (size_t)arow * 256 + skoff;
    const ushort* bp = WT + (size_t)(c0 + srow) * 256 + skoff;

    for (int kk = 0; kk < 256; kk += 32) {
        float4 x0 = *(const float4*)(ap + kk);
        float4 x1 = *(const float4*)(ap + kk + 4);
        short8 bv0 = *(const short8*)(bp + kk);
        short8 bv1 = *(const short8*)(bp + 65536 + kk);
        short8 bv2 = *(const short8*)(bp + 131072 + kk);
        __syncthreads();
        ushort a8[8] = {f2b(x0.x), f2b(x0.y), f2b(x0.z), f2b(x0.w),
                        f2b(x1.x), f2b(x1.y), f2b(x1.z), f2b(x1.w)};
        *(short8*)&As[srow * APAD + skoff] = *(const short8*)a8;
        *(short8*)&Bs[0][srow * APAD + skoff] = bv0;
        *(short8*)&Bs[1][srow * APAD + skoff] = bv1;
        *(short8*)&Bs[2][srow * APAD + skoff] = bv2;
        __syncthreads();
        short8 a0 = *(const short8*)&As[(wr * 32 +      lo) * APAD + hi * 8];
        short8 a1 = *(const short8*)&As[(wr * 32 + 16 + lo) * APAD + hi * 8];
        #pragma unroll
        for (int h = 0; h < 3; ++h) {
            short8 b0 = *(const short8*)&Bs[h][(wc * 32 +      lo) * APAD + hi * 8];
            short8 b1 = *(const short8*)&Bs[h][(wc * 32 + 16 + lo) * APAD + hi * 8];
            acc[h][0][0] = __builtin_amdgcn_mfma_f32_16x16x32_bf16(a0, b0, acc[h][0][0], 0, 0, 0);
            acc[h][0][1] = __builtin_amdgcn_mfma_f32_16x16x32_bf16(a0, b1, acc[h][0][1], 0, 0, 0);
            acc[h][1][0] = __builtin_amdgcn_mfma_f32_16x16x32_bf16(a1, b0, acc[h][1][0], 0, 0, 0);
            acc[h][1][1] = __builtin_amdgcn_mfma_f32_16x16x32_bf16(a1, b1, acc[h][1][1], 0, 0, 0);
        }
    }
    // C/D layout (HW-verified): col = lane&15, row = (lane>>4)*4 + reg
    #pragma unroll
    for (int h = 0; h < 3; ++h)
        for (int mi = 0; mi < 2; ++mi)
            for (int ni = 0; ni < 2; ++ni)
                for (int i = 0; i < 4; ++i) {
                    int row = r0 + wr * 32 + mi * 16 + hi * 4 + i;
                    int col = c0 + wc * 32 + ni * 16 + lo;
                    if (row < M) F[(size_t)h * M * 256 + (size_t)row * 256 + col] = f2b(acc[h][mi][ni][i]);
                }
}

// ---------------- per-hop GEMM (fallback) ----------------
__global__ __launch_bounds__(256) void gemm_kernel(const float* __restrict__ X,
                                                   const ushort* __restrict__ WT,
                                                   ushort* __restrict__ F, int M) {
    __shared__ ushort As[64 * APAD];
    __shared__ ushort Bs[64 * APAD];
    int tid = threadIdx.x;
    int r0 = blockIdx.x * 64, c0 = blockIdx.y * 64;
    int w = tid >> 6, lane = tid & 63;
    int wr = w >> 1, wc = w & 1;
    int lo = lane & 15, hi = lane >> 4;
    f32x4 acc[2][2] = {};
    int srow = tid >> 2;
    int skoff = (tid & 3) * 8;
    int arow = r0 + srow; if (arow > M - 1) arow = M - 1;
    const float*  ap = X + (size_t)arow * 256 + skoff;
    const ushort* bp = WT + (size_t)(c0 + srow) * 256 + skoff;
    for (int kk = 0; kk < 256; kk += 32) {
        float4 x0 = *(const float4*)(ap + kk);
        float4 x1 = *(const float4*)(ap + kk + 4);
        short8 bv = *(const short8*)(bp + kk);
        __syncthreads();
        ushort a8[8] = {f2b(x0.x), f2b(x0.y), f2b(x0.z), f2b(x0.w),
                        f2b(x1.x), f2b(x1.y), f2b(x1.z), f2b(x1.w)};
        *(short8*)&As[srow * APAD + skoff] = *(const short8*)a8;
        *(short8*)&Bs[srow * APAD + skoff] = bv;
        __syncthreads();
        short8 a0 = *(const short8*)&As[(wr * 32 +      lo) * APAD + hi * 8];
        short8 a1 = *(const short8*)&As[(wr * 32 + 16 + lo) * APAD + hi * 8];
        short8 b0 = *(const short8*)&Bs[(wc * 32 +      lo) * APAD + hi * 8];
        short8 b1 = *(const short8*)&Bs[(wc * 32 + 16 + lo) * APAD + hi * 8];
        acc[0][0] = __builtin_amdgcn_mfma_f32_16x16x32_bf16(a0, b0, acc[0][0], 0, 0, 0);
        acc[0][1] = __builtin_amdgcn_mfma_f32_16x16x32_bf16(a0, b1, acc[0][1], 0, 0, 0);
        acc[1][0] = __builtin_amdgcn_mfma_f32_16x16x32_bf16(a1, b0, acc[1][0], 0, 0, 0);
        acc[1][1] = __builtin_amdgcn_mfma_f32_16x16x32_bf16(a1, b1, acc[1][1], 0, 0, 0);
    }
    for (int mi = 0; mi < 2; ++mi)
        for (int ni = 0; ni < 2; ++ni)
            for (int i = 0; i < 4; ++i) {
                int row = r0 + wr * 32 + mi * 16 + hi * 4 + i;
                int col = c0 + wc * 32 + ni * 16 + lo;
                if (row < M) F[(size_t)row * 256 + col] = f2b(acc[mi][ni][i]);
            }
}

// ---------------- SpMM: one wave per output row, atomic-free, ILP-pipelined ----------------
// Each half-wave handles a different edge per step; lane owns 8 cols (16B loads).
// mode bit0: add previous out; bit1: apply relu
__global__ __launch_bounds__(256) void spmm_kernel(const int* __restrict__ row_ptr,
                                                   const int2* __restrict__ edges,
                                                   const ushort* __restrict__ F,
                                                   float* __restrict__ out, int n, int mode) {
    int w = threadIdx.x >> 6, lane = threadIdx.x & 63;
    int r = blockIdx.x * 4 + w;
    if (r >= n) return;
    int half = lane >> 5, l5 = lane & 31;
    int doff = l5 * 8;
    int e0 = row_ptr[r], e1 = row_ptr[r + 1];
    float acc[8] = {};
    int me = e0 + half;
    int2 ev = (me < e1) ? edges[me] : make_int2(0, 0);
    #pragma unroll 2
    for (int e = e0; e < e1; e += 2) {
        int2 cur = ev;
        int mn = e + 2 + half;
        ev = (mn < e1) ? edges[mn] : make_int2(0, 0);
        float val = __int_as_float(cur.y);
        short8 v = *(const short8*)(F + (size_t)cur.x * 256 + doff);
        #pragma unroll
        for (int i = 0; i < 8; ++i)
            acc[i] = fmaf(val, b2f((ushort)v[i]), acc[i]);
    }
    // combine the two half-wave partial sums
    #pragma unroll
    for (int i = 0; i < 8; ++i)
        acc[i] += __shfl_xor(acc[i], 32);
    // lane (half,l5) writes 16B at col l5*8 + half*4 — full 1KB row by the wave
    float4 o = half ? make_float4(acc[4], acc[5], acc[6], acc[7])
                    : make_float4(acc[0], acc[1], acc[2], acc[3]);
    float* op = out + (size_t)r * 256 + doff + half * 4;
    if (mode & 1) {
        float4 prev = *(const float4*)op;
        o.x += prev.x; o.y += prev.y; o.z += prev.z; o.w += prev.w;
    }
    if (mode & 2) {
        o.x = fmaxf(o.x, 0.f); o.y = fmaxf(o.y, 0.f);
        o.z = fmaxf(o.z, 0.f); o.w = fmaxf(o.w, 0.f);
    }
    *(float4*)op = o;
}

extern "C" void kernel_launch(void* const* d_in, const int* in_sizes, int n_in,
                              void* d_out, int out_size, void* d_ws, size_t ws_size,
                              hipStream_t stream) {
    const float* X    = (const float*)d_in[0];
    const float* W    = (const float*)d_in[1];
    const float* vals = (const float*)d_in[2];
    const int*   rows = (const int*)d_in[3];
    const int*   cols = (const int*)d_in[4];
    int n    = in_sizes[0] / D;         // 100000
    int hops = in_sizes[1] / (D * D);   // 3
    int e    = in_sizes[2] / hops;      // 3200000
    int nblk = (n + 255) / 256;         // 391 (must be <= 512 for scan_b)

    float* out = (float*)d_out;

    size_t need_fused = 0;
    {
        size_t o = 0;
        auto a = [&](size_t b) { o += (b + 255) & ~(size_t)255; };
        a((size_t)hops * D * D * 2);        // WT
        a((size_t)hops * n * D * 2);        // F (all hops)
        a((size_t)nblk * 256 * 4);          // cnt
        a(2048); a(2048);                   // bsums, bbase
        a((size_t)(n + 1) * 4);             // row_ptr
        a((size_t)hops * e * 8);            // edges
        need_fused = o;
    }

    char* wsb = (char*)d_ws;
    size_t off = 0;
    auto alloc = [&](size_t bytes) -> void* {
        void* p = wsb + off;
        off += (bytes + 255) & ~(size_t)255;
        return p;
    };

    if (ws_size >= need_fused) {
        // -------- fused path: one CSR over all hops, one GEMM, one SpMM --------
        ushort* WT      = (ushort*)alloc((size_t)hops * D * D * 2);
        ushort* F       = (ushort*)alloc((size_t)hops * n * D * 2);
        int*    cnt     = (int*)   alloc((size_t)nblk * 256 * 4);
        int*    bsums   = (int*)   alloc(2048);
        int*    bbase   = (int*)   alloc(2048);
        int*    row_ptr = (int*)   alloc((size_t)(n + 1) * 4);
        int2*   edges   = (int2*)  alloc((size_t)hops * e * 8);

        zero_int_kernel<<<nblk, 256, 0, stream>>>(cnt, nblk * 256);
        for (int h = 0; h < hops; ++h)
            hist_kernel<<<2048, 256, 0, stream>>>(rows + (size_t)h * e, cnt, e);
        scan_a_kernel<<<nblk, 256, 0, stream>>>(cnt, bsums, n);
        scan_b_kernel<<<1, 512, 0, stream>>>(bsums, bbase, nblk);
        scan_c_kernel<<<nblk, 256, 0, stream>>>(cnt, bbase, row_ptr, n, hops * e);
        zero_int_kernel<<<nblk, 256, 0, stream>>>(cnt, nblk * 256);
        for (int h = 0; h < hops; ++h)
            scatter_kernel<<<2048, 256, 0, stream>>>(rows + (size_t)h * e, cols + (size_t)h * e,
                                                     vals + (size_t)h * e, row_ptr, cnt, edges, e, h * n);

        wconv_kernel<<<(hops * D * D + 255) / 256, 256, 0, stream>>>(W, WT, hops * D * D);
        gemm3_kernel<<<dim3((n + 63) / 64, D / 64), 256, 0, stream>>>(X, WT, F, n);

        spmm_kernel<<<(n + 3) / 4, 256, 0, stream>>>(row_ptr, edges, F, out, n, 2);
    } else {
        // -------- fallback: per-hop pipeline --------
        ushort* WT      = (ushort*)alloc((size_t)hops * D * D * 2);
        ushort* F       = (ushort*)alloc((size_t)n * D * 2);
        int*    cnt     = (int*)   alloc((size_t)nblk * 256 * 4);
        int*    bsums   = (int*)   alloc(2048);
        int*    bbase   = (int*)   alloc(2048);
        int*    row_ptr = (int*)   alloc((size_t)(n + 1) * 4);
        int2*   edges   = (int2*)  alloc((size_t)e * 8);

        wconv_kernel<<<(hops * D * D + 255) / 256, 256, 0, stream>>>(W, WT, hops * D * D);
        for (int h = 0; h < hops; ++h) {
            const int*   rh = rows + (size_t)h * e;
            const int*   ch = cols + (size_t)h * e;
            const float* vh = vals + (size_t)h * e;
            zero_int_kernel<<<nblk, 256, 0, stream>>>(cnt, nblk * 256);
            hist_kernel<<<2048, 256, 0, stream>>>(rh, cnt, e);
            scan_a_kernel<<<nblk, 256, 0, stream>>>(cnt, bsums, n);
            scan_b_kernel<<<1, 512, 0, stream>>>(bsums, bbase, nblk);
            scan_c_kernel<<<nblk, 256, 0, stream>>>(cnt, bbase, row_ptr, n, e);
            zero_int_kernel<<<nblk, 256, 0, stream>>>(cnt, nblk * 256);
            scatter_kernel<<<2048, 256, 0, stream>>>(rh, ch, vh, row_ptr, cnt, edges, e, 0);
            gemm_kernel<<<dim3((n + 63) / 64, D / 64), 256, 0, stream>>>(X, WT + (size_t)h * D * D, F, n);
            int mode = (h > 0 ? 1 : 0) | (h == hops - 1 ? 2 : 0);
            spmm_kernel<<<(n + 3) / 4, 256, 0, stream>>>(row_ptr, edges, F, out, n, mode);
        }
    }
}